// Round 4
// baseline (323.683 us; speedup 1.0000x reference)
//
#include <hip/hip_runtime.h>
#include <math.h>

#define BATCH 64
#define ADIM  1152
#define BDIM  32
#define POSE  16
#define SLICE 512                    // BDIM*POSE floats per batch capsule-state
#define CHUNKS 12
#define ROWS_PER_CHUNK 96            // 1152/12
#define ROWS_PER_WAVE 24            // 96 / 4 waves
#define GROUPS 6                     // 24 rows / 4 rows-per-group
#define EPSQ 1e-6f
#define SPART_ITER ((size_t)BATCH * CHUNKS * SLICE)   // floats per iter of s_part

// ---------------------------------------------------------------------------
// route_pass<ITER>: barrier-free main loop. Each WAVE owns an independent
// 24-row strip of v; loads go global->VGPR (per-lane 64B pose rows, zero
// waste), software-pipelined in 4-row groups so ~8KB/wave stays in flight
// with no vmcnt(0) drain and no __syncthreads until the final reduction.
//   b = logits + sum_{j<ITER} p_j . v ;  c = softmax_bc(b) (no max-subtract:
//   |b| <= ~17 since ||p||<1, safe in fp32) ;  s_partial = sum_a c*v
// ---------------------------------------------------------------------------
template<int ITER>
__global__ __launch_bounds__(256) void route_pass(
    const float* __restrict__ v,       // [BATCH][ADIM][BDIM][POSE]
    const float* __restrict__ logits,  // [ADIM][BDIM]
    const float* __restrict__ p_buf,   // [2][BATCH][SLICE]
    float* __restrict__ s_out)         // [BATCH][CHUNKS][SLICE]
{
    const int bt    = blockIdx.x / CHUNKS;
    const int chunk = blockIdx.x % CHUNKS;
    const int t     = threadIdx.x;
    const int wv    = t >> 6;
    const int lane  = t & 63;
    const int bc    = lane & 31;   // capsule (softmax dim)
    const int a_sub = lane >> 5;   // 0/1: row parity within a pair

    // loop-invariant p fragments in registers
    float p0[POSE], p1[POSE];
    if (ITER >= 1) {
        const float4* pp = (const float4*)(p_buf + (size_t)bt * SLICE + bc * POSE);
#pragma unroll
        for (int q = 0; q < 4; ++q) {
            float4 f = pp[q];
            p0[4*q+0]=f.x; p0[4*q+1]=f.y; p0[4*q+2]=f.z; p0[4*q+3]=f.w;
        }
    }
    if (ITER >= 2) {
        const float4* pp = (const float4*)(p_buf + (size_t)(BATCH + bt) * SLICE + bc * POSE);
#pragma unroll
        for (int q = 0; q < 4; ++q) {
            float4 f = pp[q];
            p1[4*q+0]=f.x; p1[4*q+1]=f.y; p1[4*q+2]=f.z; p1[4*q+3]=f.w;
        }
    }

    float acc[POSE];
#pragma unroll
    for (int k = 0; k < POSE; ++k) acc[k] = 0.f;

    const int row0 = chunk * ROWS_PER_CHUNK + wv * ROWS_PER_WAVE;
    const float* base = v + ((size_t)bt * ADIM + row0) * SLICE;

    // two register pipeline buffers, 2 rows per lane each (4 rows per group)
    float vA[2][POSE], vB[2][POSE];

    auto load_group = [&](float (*dst)[POSE], int g) {
#pragma unroll
        for (int j = 0; j < 2; ++j) {
            const float4* p4 = (const float4*)(base + (size_t)(g * 4 + 2 * j + a_sub) * SLICE + bc * POSE);
#pragma unroll
            for (int q = 0; q < 4; ++q) {
                float4 f = p4[q];
                dst[j][4*q+0]=f.x; dst[j][4*q+1]=f.y; dst[j][4*q+2]=f.z; dst[j][4*q+3]=f.w;
            }
        }
    };

    auto compute_group = [&](float (*vv)[POSE], int g) {
#pragma unroll
        for (int j = 0; j < 2; ++j) {
            const int a = row0 + g * 4 + 2 * j + a_sub;
            float bval = logits[a * BDIM + bc];
            if (ITER >= 1) {
                float d = 0.f;
#pragma unroll
                for (int k = 0; k < POSE; ++k) d = fmaf(p0[k], vv[j][k], d);
                bval += d;
            }
            if (ITER >= 2) {
                float d = 0.f;
#pragma unroll
                for (int k = 0; k < POSE; ++k) d = fmaf(p1[k], vv[j][k], d);
                bval += d;
            }
            // softmax over 32 capsules, no max pass (|bval| bounded ~17)
            float e = __expf(bval);
            float ssum = e;
#pragma unroll
            for (int off = 16; off > 0; off >>= 1)
                ssum += __shfl_xor(ssum, off, 32);
            float c = e / ssum;
#pragma unroll
            for (int k = 0; k < POSE; ++k) acc[k] = fmaf(c, vv[j][k], acc[k]);
        }
    };

    load_group(vA, 0);
#pragma unroll
    for (int g = 0; g < GROUPS; ++g) {
        float (*cur)[POSE] = (g & 1) ? vB : vA;
        float (*nxt)[POSE] = (g & 1) ? vA : vB;
        if (g + 1 < GROUPS) load_group(nxt, g + 1);
        compute_group(cur, g);
    }

    // single-barrier reduction of the 8 (wave, a_sub) partials
    __shared__ float red[8 * SLICE];   // 16 KB
#pragma unroll
    for (int k = 0; k < POSE; ++k)
        red[(wv * 2 + a_sub) * SLICE + bc * POSE + k] = acc[k];
    __syncthreads();

    for (int idx = t; idx < SLICE; idx += 256) {
        float s = 0.f;
#pragma unroll
        for (int w = 0; w < 8; ++w) s += red[w * SLICE + idx];
        s_out[((size_t)bt * CHUNKS + chunk) * SLICE + idx] = s;
    }
}

// reduce chunk partials for iter j and squash -> p_buf[j]
__global__ __launch_bounds__(512) void squash_pass(
    const float* __restrict__ s_part_j,  // [bt][CHUNKS][SLICE]
    float* __restrict__ p_out_j)         // [BATCH][SLICE]
{
    const int bt = blockIdx.x;
    const int t  = threadIdx.x;          // t = bc*16 + pose

    __shared__ float sq[SLICE];
    __shared__ float fac[POSE];

    float sv = 0.f;
#pragma unroll
    for (int c = 0; c < CHUNKS; ++c)
        sv += s_part_j[((size_t)bt * CHUNKS + c) * SLICE + t];

    sq[t] = sv * sv;
    __syncthreads();
    if (t < POSE) {
        float n = 0.f;
        for (int b2 = 0; b2 < BDIM; ++b2) n += sq[b2 * POSE + t];
        fac[t] = sqrtf(n + EPSQ) / (1.f + n);
    }
    __syncthreads();
    p_out_j[(size_t)bt * SLICE + t] = fac[t & 15] * sv;
}

// final: reduce iter-2 chunk partials, squash, emit a_out (8192) ++ p (32768)
__global__ __launch_bounds__(512) void final_out(
    const float* __restrict__ s_part2,  // [bt][CHUNKS][SLICE]
    float* __restrict__ out)
{
    const int bt = blockIdx.x;
    const int t  = threadIdx.x;        // t = bc*16 + pose
    const int pose = t & 15;

    __shared__ float sq[SLICE];
    __shared__ float ns[POSE];

    float sv = 0.f;
#pragma unroll
    for (int c = 0; c < CHUNKS; ++c)
        sv += s_part2[((size_t)bt * CHUNKS + c) * SLICE + t];

    sq[t] = sv * sv;
    __syncthreads();
    if (t < POSE) {
        float a = 0.f;
        for (int b2 = 0; b2 < BDIM; ++b2) a += sq[b2 * POSE + t];
        ns[t] = a;
    }
    __syncthreads();
    float n = ns[pose];
    float pv = sqrtf(n + EPSQ) / (1.f + n) * sv;

    out[8192 + bt * SLICE + t] = pv;
    sq[t] = pv * pv;
    __syncthreads();
    // a_out[bt][bc][p2] = sqrt(sum_p1 p[bc][p1][p2]^2)
    if (t < 128) {
        int b2 = t >> 2, p2 = t & 3;
        float a = 0.f;
#pragma unroll
        for (int p1 = 0; p1 < 4; ++p1) a += sq[b2 * POSE + p1 * 4 + p2];
        out[bt * 128 + b2 * 4 + p2] = sqrtf(a);
    }
}

extern "C" void kernel_launch(void* const* d_in, const int* in_sizes, int n_in,
                              void* d_out, int out_size, void* d_ws, size_t ws_size,
                              hipStream_t stream) {
    const float* v      = (const float*)d_in[1];   // (64,1152,32,4,4,1)
    const float* logits = (const float*)d_in[2];   // (1,1152,32,1,1,1)
    float* out = (float*)d_out;

    // ws layout: s_part[3][BATCH][CHUNKS][SLICE] (4.5 MB) ++ p_buf[2][BATCH][SLICE]
    // every element written before read -> no memset needed
    float* s_part = (float*)d_ws;
    float* p_buf  = s_part + 3 * SPART_ITER;

    route_pass<0><<<dim3(BATCH * CHUNKS), dim3(256), 0, stream>>>(
        v, logits, p_buf, s_part + 0 * SPART_ITER);
    squash_pass<<<dim3(BATCH), dim3(512), 0, stream>>>(
        s_part + 0 * SPART_ITER, p_buf);
    route_pass<1><<<dim3(BATCH * CHUNKS), dim3(256), 0, stream>>>(
        v, logits, p_buf, s_part + 1 * SPART_ITER);
    squash_pass<<<dim3(BATCH), dim3(512), 0, stream>>>(
        s_part + 1 * SPART_ITER, p_buf + (size_t)BATCH * SLICE);
    route_pass<2><<<dim3(BATCH * CHUNKS), dim3(256), 0, stream>>>(
        v, logits, p_buf, s_part + 2 * SPART_ITER);
    final_out<<<dim3(BATCH), dim3(512), 0, stream>>>(
        s_part + 2 * SPART_ITER, out);
}

// Round 5
// 269.587 us; speedup vs baseline: 1.2007x; 1.2007x over previous
//
#include <hip/hip_runtime.h>
#include <math.h>

#define BATCH 64
#define ADIM  1152
#define BDIM  32
#define POSE  16
#define SLICE 512                    // BDIM*POSE floats per batch capsule-state
#define CHUNKS 16
#define WAVES 4
#define ROWS_PER_WAVE 18             // 1152 / (CHUNKS*WAVES)
#define G 3                          // rows per pipeline group
#define NGROUPS 6                    // ROWS_PER_WAVE / G
#define EPSQ 1e-6f
#define SPART_ITER ((size_t)BATCH * CHUNKS * SLICE)

// ---------------------------------------------------------------------------
// Fragment mapping: lane l <-> (bc = l>>2, quad = l&3), two halves per lane
// (half0: bc 0..15, half1: bc 16..31). With this mapping the contiguous wave
// load IS the compute layout:
//   v row float4s:  row4[lane] (half0), row4[64+lane] (half1)  -- 1KB/instr
//   p fragments:    p4[lane],  p4[64+lane]
//   s accumulator:  slot lane, slot 64+lane
// Main loop: NO LDS, NO barriers, only contiguous VMEM, register-double-
// buffered 3-row groups. Dots reduce via shfl_xor(1,2) within quads; softmax
// denominator via shfl_xor(4,8,16,32) butterfly. dot(p0,v)+dot(p1,v) merges
// into dot(p0+p1, v). Softmax needs no max-subtract: |b| <= ~20 in fp32.
// ---------------------------------------------------------------------------
template<int ITER>
__global__ __launch_bounds__(256) void route_pass(
    const float* __restrict__ v,       // [BATCH][ADIM][BDIM][POSE]
    const float* __restrict__ logits,  // [ADIM][BDIM]
    const float* __restrict__ p_buf,   // [2][BATCH][SLICE]
    float* __restrict__ s_out)         // [BATCH][CHUNKS][SLICE]
{
    const int bt    = blockIdx.x / CHUNKS;
    const int chunk = blockIdx.x % CHUNKS;
    const int t     = threadIdx.x;
    const int wv    = t >> 6;
    const int lane  = t & 63;
    const int bq    = lane >> 2;       // bc within half (0..15)

    const int row0 = (chunk * WAVES + wv) * ROWS_PER_WAVE;

    // psum = p0 (+ p1): lane's float4 fragments for both halves
    float4 psA = make_float4(0.f, 0.f, 0.f, 0.f);
    float4 psB = make_float4(0.f, 0.f, 0.f, 0.f);
    if (ITER >= 1) {
        const float4* pp = (const float4*)(p_buf + (size_t)bt * SLICE);
        psA = pp[lane];
        psB = pp[64 + lane];
    }
    if (ITER >= 2) {
        const float4* pp = (const float4*)(p_buf + (size_t)(BATCH + bt) * SLICE);
        float4 a = pp[lane], b = pp[64 + lane];
        psA.x += a.x; psA.y += a.y; psA.z += a.z; psA.w += a.w;
        psB.x += b.x; psB.y += b.y; psB.z += b.z; psB.w += b.w;
    }

    // preload this wave's logits strip: 18 rows x 32 = 576 floats, 9/lane
    float lg[9];
    {
        const float* lbase = logits + row0 * BDIM;
#pragma unroll
        for (int i = 0; i < 9; ++i) lg[i] = lbase[i * 64 + lane];
    }

    float4 acc0 = make_float4(0.f, 0.f, 0.f, 0.f);
    float4 acc1 = make_float4(0.f, 0.f, 0.f, 0.f);

    const float4* vb4 = (const float4*)(v + ((size_t)bt * ADIM + row0) * SLICE);

    float4 bufA[G][2], bufB[G][2];

    auto load_group = [&](float4 (*buf)[2], int g) {
#pragma unroll
        for (int r = 0; r < G; ++r) {
            buf[r][0] = vb4[(g * G + r) * 128 + lane];
            buf[r][1] = vb4[(g * G + r) * 128 + 64 + lane];
        }
    };

    auto compute_group = [&](float4 (*buf)[2], int g) {
#pragma unroll
        for (int r = 0; r < G; ++r) {
            const int ar = g * G + r;            // wave-local row index
            float4 va = buf[r][0];
            float4 vb = buf[r][1];

            // logits via shfl from the preloaded strip (reg idx is constant-folded)
            const int base0 = ar * 32;
            const int base1 = ar * 32 + 16;
            float b0 = __shfl(lg[base0 >> 6], (base0 & 63) + bq, 64);
            float b1 = __shfl(lg[base1 >> 6], (base1 & 63) + bq, 64);

            if (ITER >= 1) {
                float d0 = psA.x * va.x + psA.y * va.y + psA.z * va.z + psA.w * va.w;
                float d1 = psB.x * vb.x + psB.y * vb.y + psB.z * vb.z + psB.w * vb.w;
                d0 += __shfl_xor(d0, 1, 64); d0 += __shfl_xor(d0, 2, 64);
                d1 += __shfl_xor(d1, 1, 64); d1 += __shfl_xor(d1, 2, 64);
                b0 += d0; b1 += d1;
            }

            float e0 = __expf(b0);
            float e1 = __expf(b1);
            float u = e0 + e1;
#pragma unroll
            for (int off = 4; off <= 32; off <<= 1)
                u += __shfl_xor(u, off, 64);
            float rd = __builtin_amdgcn_rcpf(u);
            float c0 = e0 * rd;
            float c1 = e1 * rd;

            acc0.x = fmaf(c0, va.x, acc0.x); acc0.y = fmaf(c0, va.y, acc0.y);
            acc0.z = fmaf(c0, va.z, acc0.z); acc0.w = fmaf(c0, va.w, acc0.w);
            acc1.x = fmaf(c1, vb.x, acc1.x); acc1.y = fmaf(c1, vb.y, acc1.y);
            acc1.z = fmaf(c1, vb.z, acc1.z); acc1.w = fmaf(c1, vb.w, acc1.w);
        }
    };

    load_group(bufA, 0);
#pragma unroll
    for (int g = 0; g < NGROUPS; ++g) {
        float4 (*cur)[2] = (g & 1) ? bufB : bufA;
        float4 (*nxt)[2] = (g & 1) ? bufA : bufB;
        if (g + 1 < NGROUPS) load_group(nxt, g + 1);
        compute_group(cur, g);
    }

    // single-barrier cross-wave reduction (LDS only here)
    __shared__ float4 red[WAVES * 128];   // 8 KB
    red[wv * 128 + lane] = acc0;
    red[wv * 128 + 64 + lane] = acc1;
    __syncthreads();

    if (t < 128) {
        float4 s = red[t];
#pragma unroll
        for (int w = 1; w < WAVES; ++w) {
            float4 x = red[w * 128 + t];
            s.x += x.x; s.y += x.y; s.z += x.z; s.w += x.w;
        }
        ((float4*)(s_out + ((size_t)bt * CHUNKS + chunk) * SLICE))[t] = s;
    }
}

// reduce chunk partials for iter j and squash -> p_buf[j]
__global__ __launch_bounds__(512) void squash_pass(
    const float* __restrict__ s_part_j,  // [bt][CHUNKS][SLICE]
    float* __restrict__ p_out_j)         // [BATCH][SLICE]
{
    const int bt = blockIdx.x;
    const int t  = threadIdx.x;          // t = bc*16 + pose

    __shared__ float sq[SLICE];
    __shared__ float fac[POSE];

    float sv = 0.f;
#pragma unroll
    for (int c = 0; c < CHUNKS; ++c)
        sv += s_part_j[((size_t)bt * CHUNKS + c) * SLICE + t];

    sq[t] = sv * sv;
    __syncthreads();
    if (t < POSE) {
        float n = 0.f;
        for (int b2 = 0; b2 < BDIM; ++b2) n += sq[b2 * POSE + t];
        fac[t] = sqrtf(n + EPSQ) / (1.f + n);
    }
    __syncthreads();
    p_out_j[(size_t)bt * SLICE + t] = fac[t & 15] * sv;
}

// final: reduce iter-2 chunk partials, squash, emit a_out (8192) ++ p (32768)
__global__ __launch_bounds__(512) void final_out(
    const float* __restrict__ s_part2,  // [bt][CHUNKS][SLICE]
    float* __restrict__ out)
{
    const int bt = blockIdx.x;
    const int t  = threadIdx.x;        // t = bc*16 + pose
    const int pose = t & 15;

    __shared__ float sq[SLICE];
    __shared__ float ns[POSE];

    float sv = 0.f;
#pragma unroll
    for (int c = 0; c < CHUNKS; ++c)
        sv += s_part2[((size_t)bt * CHUNKS + c) * SLICE + t];

    sq[t] = sv * sv;
    __syncthreads();
    if (t < POSE) {
        float a = 0.f;
        for (int b2 = 0; b2 < BDIM; ++b2) a += sq[b2 * POSE + t];
        ns[t] = a;
    }
    __syncthreads();
    float n = ns[pose];
    float pv = sqrtf(n + EPSQ) / (1.f + n) * sv;

    out[8192 + bt * SLICE + t] = pv;
    sq[t] = pv * pv;
    __syncthreads();
    // a_out[bt][bc][p2] = sqrt(sum_p1 p[bc][p1][p2]^2)
    if (t < 128) {
        int b2 = t >> 2, p2 = t & 3;
        float a = 0.f;
#pragma unroll
        for (int p1 = 0; p1 < 4; ++p1) a += sq[b2 * POSE + p1 * 4 + p2];
        out[bt * 128 + b2 * 4 + p2] = sqrtf(a);
    }
}

extern "C" void kernel_launch(void* const* d_in, const int* in_sizes, int n_in,
                              void* d_out, int out_size, void* d_ws, size_t ws_size,
                              hipStream_t stream) {
    const float* v      = (const float*)d_in[1];   // (64,1152,32,4,4,1)
    const float* logits = (const float*)d_in[2];   // (1,1152,32,1,1,1)
    float* out = (float*)d_out;

    // ws: s_part[3][BATCH][CHUNKS][SLICE] (6 MB) ++ p_buf[2][BATCH][SLICE]
    // every element written before read -> no memset needed
    float* s_part = (float*)d_ws;
    float* p_buf  = s_part + 3 * SPART_ITER;

    route_pass<0><<<dim3(BATCH * CHUNKS), dim3(256), 0, stream>>>(
        v, logits, p_buf, s_part + 0 * SPART_ITER);
    squash_pass<<<dim3(BATCH), dim3(512), 0, stream>>>(
        s_part + 0 * SPART_ITER, p_buf);
    route_pass<1><<<dim3(BATCH * CHUNKS), dim3(256), 0, stream>>>(
        v, logits, p_buf, s_part + 1 * SPART_ITER);
    squash_pass<<<dim3(BATCH), dim3(512), 0, stream>>>(
        s_part + 1 * SPART_ITER, p_buf + (size_t)BATCH * SLICE);
    route_pass<2><<<dim3(BATCH * CHUNKS), dim3(256), 0, stream>>>(
        v, logits, p_buf, s_part + 2 * SPART_ITER);
    final_out<<<dim3(BATCH), dim3(512), 0, stream>>>(
        s_part + 2 * SPART_ITER, out);
}

// Round 8
// 257.855 us; speedup vs baseline: 1.2553x; 1.0455x over previous
//
#include <hip/hip_runtime.h>
#include <math.h>

#define BATCH 64
#define ADIM  1152
#define BDIM  32
#define POSE  16
#define SLICE 512                 // BDIM*POSE floats per batch capsule-state
#define CHUNKS 16
#define ROWS  72                  // rows per block = ADIM/CHUNKS
#define RPW   18                  // rows per wave (4 waves)
#define WAVES 4
#define EPSQ  1e-6f
#define SPART_ITER ((size_t)BATCH * CHUNKS * SLICE)

typedef float v4f __attribute__((ext_vector_type(4)));

// pack two floats -> bf16x2 (round-to-nearest-even)
__device__ __forceinline__ unsigned pack_bf16x2(float a, float b) {
    unsigned ua = __float_as_uint(a), ub = __float_as_uint(b);
    ua = (ua + 0x7fffu + ((ua >> 16) & 1u)) >> 16;
    ub = (ub + 0x7fffu + ((ub >> 16) & 1u));
    return (ua & 0xffffu) | (ub & 0xffff0000u);
}

__device__ __forceinline__ v4f unpack_bf16x4(uint2 w) {
    v4f r;
    r.x = __uint_as_float(w.x << 16);
    r.y = __uint_as_float(w.x & 0xffff0000u);
    r.z = __uint_as_float(w.y << 16);
    r.w = __uint_as_float(w.y & 0xffff0000u);
    return r;
}

// ---------------------------------------------------------------------------
// Pass 0: stream fp32 v once (coalesced, nontemporal), write bf16 tile to ws
// (L3-resident for passes 1-2), accumulate s0 = sum_a softmax(logits)*v from
// the full-precision data in the same loop. c0 weights precomputed in LDS.
// ---------------------------------------------------------------------------
__global__ __launch_bounds__(256) void route0_compress(
    const float* __restrict__ v,       // [BATCH][ADIM][BDIM][POSE]
    const float* __restrict__ logits,  // [ADIM][BDIM]
    uint2* __restrict__ tile,          // bf16 copy of v, same layout (uint2 = f4 slot)
    float* __restrict__ s_part)        // [BATCH][CHUNKS][SLICE]
{
    const int bt    = blockIdx.x >> 4;
    const int chunk = blockIdx.x & 15;
    const int t     = threadIdx.x;
    const int bc0   = (t >> 2) & 31;   // fixed bc of this thread's stream slots
    const int hi    = t >> 7;          // row = 2k + hi for f4-index i = t + 256k
    const int a0    = chunk * ROWS;

    __shared__ float w_sh[ROWS * BDIM];   // 9 KB: softmax(logits) weights
    __shared__ v4f   red[128];            // 2 KB

    if (t < ROWS) {
        const float* lr = logits + (size_t)(a0 + t) * BDIM;
        float s = 0.f;
        float e[BDIM];
#pragma unroll
        for (int b = 0; b < BDIM; ++b) { e[b] = __expf(lr[b]); s += e[b]; }
        float rd = 1.f / s;
#pragma unroll
        for (int b = 0; b < BDIM; ++b) w_sh[t * BDIM + b] = e[b] * rd;
    }
    __syncthreads();

    const v4f* vg = (const v4f*)(v + ((size_t)bt * ADIM + a0) * SLICE);
    uint2*     tg = tile + ((size_t)bt * ADIM + a0) * 128;

    v4f acc = (v4f){0.f, 0.f, 0.f, 0.f};
    v4f fA[6], fB[6];
#pragma unroll
    for (int u = 0; u < 6; ++u)
        fA[u] = __builtin_nontemporal_load(&vg[t + 256 * u]);

#pragma unroll
    for (int kk = 0; kk < 6; ++kk) {
        v4f* cur = (kk & 1) ? fB : fA;
        v4f* nxt = (kk & 1) ? fA : fB;
        if (kk + 1 < 6) {
#pragma unroll
            for (int u = 0; u < 6; ++u)
                nxt[u] = __builtin_nontemporal_load(&vg[t + 256 * ((kk + 1) * 6 + u)]);
        }
#pragma unroll
        for (int u = 0; u < 6; ++u) {
            const int k   = kk * 6 + u;
            const int i   = t + 256 * k;
            const int row = 2 * k + hi;
            tg[i] = make_uint2(pack_bf16x2(cur[u].x, cur[u].y),
                               pack_bf16x2(cur[u].z, cur[u].w));
            float c0 = w_sh[row * BDIM + bc0];
            acc += c0 * cur[u];
        }
    }

    // pair-reduce (t, t+128): thread t<128 owns f4 slot t of the s vector
    __syncthreads();
    if (t >= 128) red[t - 128] = acc;
    __syncthreads();
    if (t < 128) {
        acc += red[t];
        ((v4f*)(s_part + ((size_t)bt * CHUNKS + chunk) * SLICE))[t] = acc;
    }
}

// ---------------------------------------------------------------------------
// Passes 1/2 from the bf16 tile. Fragment mapping per wave: lane l <->
// (bc = l>>2 [+16 half1], q = l&3). Dots via shfl_xor(1,2); softmax denom via
// shfl_xor(4..32). psum = accumulated sum of p_j (b = logits + psum . v).
// No max-subtract: |b| bounded (~20) in fp32.
// ---------------------------------------------------------------------------
__global__ __launch_bounds__(256) void route_next(
    const uint2* __restrict__ tile,
    const float* __restrict__ logits,
    const float* __restrict__ psum_g,  // [BATCH][SLICE]
    float* __restrict__ s_out)         // [BATCH][CHUNKS][SLICE]
{
    const int bt    = blockIdx.x >> 4;
    const int chunk = blockIdx.x & 15;
    const int t     = threadIdx.x;
    const int lane  = t & 63;
    const int wv    = t >> 6;
    const int bq    = lane >> 2;
    const int a0    = chunk * ROWS;

    __shared__ v4f red[WAVES * 128];   // 8 KB

    const v4f* pp = (const v4f*)(psum_g + (size_t)bt * SLICE);
    v4f psA = pp[lane];
    v4f psB = pp[64 + lane];
    v4f acc0 = (v4f){0.f, 0.f, 0.f, 0.f};
    v4f acc1 = (v4f){0.f, 0.f, 0.f, 0.f};

    const int r0 = wv * RPW;
    const uint2* tb = tile + ((size_t)bt * ADIM + a0) * 128;

#pragma unroll 6
    for (int r = 0; r < RPW; ++r) {
        const int rw = r0 + r;
        uint2 wa = tb[rw * 128 + lane];
        uint2 wb = tb[rw * 128 + 64 + lane];
        v4f va = unpack_bf16x4(wa);
        v4f vb = unpack_bf16x4(wb);
        float b0 = logits[(size_t)(a0 + rw) * BDIM + bq];
        float b1 = logits[(size_t)(a0 + rw) * BDIM + 16 + bq];
        float d0 = psA.x * va.x + psA.y * va.y + psA.z * va.z + psA.w * va.w;
        float d1 = psB.x * vb.x + psB.y * vb.y + psB.z * vb.z + psB.w * vb.w;
        d0 += __shfl_xor(d0, 1, 64); d0 += __shfl_xor(d0, 2, 64);
        d1 += __shfl_xor(d1, 1, 64); d1 += __shfl_xor(d1, 2, 64);
        float e0 = __expf(b0 + d0);
        float e1 = __expf(b1 + d1);
        float uu = e0 + e1;
#pragma unroll
        for (int off = 4; off <= 32; off <<= 1)
            uu += __shfl_xor(uu, off, 64);
        float rd = __builtin_amdgcn_rcpf(uu);
        float c0 = e0 * rd, c1 = e1 * rd;
        acc0 += c0 * va;
        acc1 += c1 * vb;
    }

    // cross-wave reduce (f4 slots: acc0 -> lane, acc1 -> 64+lane)
    __syncthreads();
    if (wv == 3) { red[lane] = acc0; red[64 + lane] = acc1; }
    __syncthreads();
    if (wv == 2) { red[lane] += acc0; red[64 + lane] += acc1; }
    __syncthreads();
    if (wv == 1) { red[lane] += acc0; red[64 + lane] += acc1; }
    __syncthreads();
    if (wv == 0) {
        v4f* sp = (v4f*)(s_out + ((size_t)bt * CHUNKS + chunk) * SLICE);
        sp[lane]      = red[lane] + acc0;
        sp[64 + lane] = red[64 + lane] + acc1;
    }
}

// reduce chunk partials for iter j, squash, accumulate psum (+= if add)
__global__ __launch_bounds__(512) void squash_pass(
    const float* __restrict__ s_part_j,  // [bt][CHUNKS][SLICE]
    float* __restrict__ psum,            // [BATCH][SLICE]
    int add)
{
    const int bt = blockIdx.x;
    const int t  = threadIdx.x;          // t = bc*16 + pose

    __shared__ float sq[SLICE];
    __shared__ float fac[POSE];

    float sv = 0.f;
#pragma unroll
    for (int c = 0; c < CHUNKS; ++c)
        sv += s_part_j[((size_t)bt * CHUNKS + c) * SLICE + t];

    sq[t] = sv * sv;
    __syncthreads();
    if (t < POSE) {
        float n = 0.f;
        for (int b2 = 0; b2 < BDIM; ++b2) n += sq[b2 * POSE + t];
        fac[t] = sqrtf(n + EPSQ) / (1.f + n);
    }
    __syncthreads();
    float prev = add ? psum[(size_t)bt * SLICE + t] : 0.f;
    psum[(size_t)bt * SLICE + t] = prev + fac[t & 15] * sv;
}

// final: reduce iter-2 chunk partials, squash, emit a_out (8192) ++ p (32768)
__global__ __launch_bounds__(512) void final_out(
    const float* __restrict__ s_part2,  // [bt][CHUNKS][SLICE]
    float* __restrict__ out)
{
    const int bt = blockIdx.x;
    const int t  = threadIdx.x;        // t = bc*16 + pose
    const int pose = t & 15;

    __shared__ float sq[SLICE];
    __shared__ float ns[POSE];

    float sv = 0.f;
#pragma unroll
    for (int c = 0; c < CHUNKS; ++c)
        sv += s_part2[((size_t)bt * CHUNKS + c) * SLICE + t];

    sq[t] = sv * sv;
    __syncthreads();
    if (t < POSE) {
        float a = 0.f;
        for (int b2 = 0; b2 < BDIM; ++b2) a += sq[b2 * POSE + t];
        ns[t] = a;
    }
    __syncthreads();
    float n = ns[pose];
    float pv = sqrtf(n + EPSQ) / (1.f + n) * sv;

    out[8192 + (size_t)bt * SLICE + t] = pv;
    sq[t] = pv * pv;
    __syncthreads();
    // a_out[bt][b2][p2] = sqrt(sum_p1 p[b2][p1][p2]^2)
    if (t < 128) {
        const int b2 = t >> 2, p2 = t & 3;
        float a = 0.f;
#pragma unroll
        for (int p1 = 0; p1 < 4; ++p1) a += sq[b2 * POSE + p1 * 4 + p2];
        out[(size_t)bt * 128 + t] = sqrtf(a);
    }
}

extern "C" void kernel_launch(void* const* d_in, const int* in_sizes, int n_in,
                              void* d_out, int out_size, void* d_ws, size_t ws_size,
                              hipStream_t stream) {
    const float* v      = (const float*)d_in[1];   // (64,1152,32,4,4,1)
    const float* logits = (const float*)d_in[2];   // (1,1152,32,1,1,1)
    float* out = (float*)d_out;

    // ws: bf16 tile (75.5 MB) ++ s_part[3][BATCH][CHUNKS][SLICE] (6 MB)
    //     ++ psum[BATCH][SLICE] (128 KB). All written before read -> no memset.
    uint2* tile   = (uint2*)d_ws;
    float* s_part = (float*)((char*)d_ws + (size_t)BATCH * ADIM * 128 * sizeof(uint2));
    float* psum   = s_part + 3 * SPART_ITER;

    route0_compress<<<dim3(BATCH * CHUNKS), dim3(256), 0, stream>>>(
        v, logits, tile, s_part + 0 * SPART_ITER);
    squash_pass<<<dim3(BATCH), dim3(512), 0, stream>>>(
        s_part + 0 * SPART_ITER, psum, 0);
    route_next<<<dim3(BATCH * CHUNKS), dim3(256), 0, stream>>>(
        tile, logits, psum, s_part + 1 * SPART_ITER);
    squash_pass<<<dim3(BATCH), dim3(512), 0, stream>>>(
        s_part + 1 * SPART_ITER, psum, 1);
    route_next<<<dim3(BATCH * CHUNKS), dim3(256), 0, stream>>>(
        tile, logits, psum, s_part + 2 * SPART_ITER);
    final_out<<<dim3(BATCH), dim3(512), 0, stream>>>(
        s_part + 2 * SPART_ITER, out);
}